// Round 2
// baseline (178.409 us; speedup 1.0000x reference)
//
#include <hip/hip_runtime.h>
#include <hip/hip_bf16.h>

// AdditiveAttention: B=8, Lq=128, Lk=512, Dq=Dk=H=Dv=256, fp32.
// out = softmax(mask(tanh(q[:,None]+k[None,:]) . wv)) @ V
//
// ws layout (floats): qproj[1024*256] | kproj[4096*256] | scores[1024*512]
//   total 7,340,032 bytes.

#define SCALE_2LOG2E 2.885390081777927f   // 2*log2(e): tanh(x) uses 2^(x*2log2e)
#define LOG2E        1.4426950408889634f
#define MASK_VALUE  -1000000.0f

__device__ __forceinline__ float fast_exp2(float x) {
#if __has_builtin(__builtin_amdgcn_exp2f)
    return __builtin_amdgcn_exp2f(x);
#else
    return exp2f(x);
#endif
}
__device__ __forceinline__ float fast_rcp(float x) {
#if __has_builtin(__builtin_amdgcn_rcpf)
    return __builtin_amdgcn_rcpf(x);
#else
    return 1.0f / x;
#endif
}

// P[M][256] = (X[M][256] @ W[256][256]) * scale ; 16 rows per block, 256 threads.
__global__ __launch_bounds__(256) void proj_kernel(
    const float* __restrict__ X, const float* __restrict__ W,
    float* __restrict__ P, float scale)
{
    __shared__ float xs[16][256];
    const int t = threadIdx.x;
    const int row0 = blockIdx.x * 16;

    // stage X tile (16*256 floats = 1024 float4)
    const float4* src = (const float4*)(X + row0 * 256);
    float4* dst = (float4*)&xs[0][0];
    for (int i = t; i < 1024; i += 256) dst[i] = src[i];
    __syncthreads();

    const int col = t;
    float acc[16];
#pragma unroll
    for (int r = 0; r < 16; ++r) acc[r] = 0.0f;

    for (int d = 0; d < 256; d += 4) {
        const float w0 = W[(d + 0) * 256 + col];
        const float w1 = W[(d + 1) * 256 + col];
        const float w2 = W[(d + 2) * 256 + col];
        const float w3 = W[(d + 3) * 256 + col];
#pragma unroll
        for (int r = 0; r < 16; ++r) {
            float4 a = *(const float4*)&xs[r][d];   // broadcast across lanes
            acc[r] += a.x * w0 + a.y * w1 + a.z * w2 + a.w * w3;
        }
    }
#pragma unroll
    for (int r = 0; r < 16; ++r)
        P[(row0 + r) * 256 + col] = acc[r] * scale;
}

// scores[b][q][k] = sum_h tanh-style reduction. qproj/kproj are pre-scaled by
// 2*log2(e), so tanh(q+k) = 1 - 2/(2^(q'+k') + 1).
// Block: 256 threads = 16 q-rows x 16 h-groups; K-tile of 32 staged in LDS.
__global__ __launch_bounds__(256) void score_kernel(
    const float* __restrict__ qproj,   // [B*128][256] pre-scaled
    const float* __restrict__ kproj,   // [B*512][256] pre-scaled
    const float* __restrict__ wv,      // [256] (unscaled)
    const int*   __restrict__ valid_lens,
    float* __restrict__ scores)        // [B*128][512]
{
    const int b  = blockIdx.z;
    const int q0 = blockIdx.y * 16;
    const int k0 = blockIdx.x * 32;

    __shared__ float ks[32][260];      // +4 pad: conflict-free strided reads
    const int t = threadIdx.x;

    { // stage K tile: 32 rows x 64 float4
        const float4* src = (const float4*)(kproj + (b * 512 + k0) * 256);
        for (int idx = t; idx < 32 * 64; idx += 256) {
            const int row = idx >> 6, c4 = idx & 63;
            *(float4*)&ks[row][c4 * 4] = src[row * 64 + c4];
        }
    }

    const int hg = t & 15;     // h sub-lane: h = hg + 16*i
    const int ql = t >> 4;     // q row 0..15

    float qreg[16], wreg[16];
    const float* qrow = qproj + (b * 128 + q0 + ql) * 256;
#pragma unroll
    for (int i = 0; i < 16; ++i) {
        qreg[i] = qrow[hg + 16 * i];
        wreg[i] = wv[hg + 16 * i];
    }
    __syncthreads();

    const int vlen = valid_lens[b];
    float* srow = scores + (b * 128 + q0 + ql) * 512 + k0;

    for (int k = 0; k < 32; ++k) {
        float s = 0.0f;
#pragma unroll
        for (int i = 0; i < 16; ++i) {
            const float a = qreg[i] + ks[k][hg + 16 * i];  // conflict-free
            const float e = fast_exp2(a);                  // 2^(2x*log2e) = e^(2x)
            const float r = fast_rcp(e + 1.0f);
            s += wreg[i] * (1.0f - 2.0f * r);              // wv * tanh
        }
        s += __shfl_xor(s, 1);
        s += __shfl_xor(s, 2);
        s += __shfl_xor(s, 4);
        s += __shfl_xor(s, 8);
        if (hg == 0)
            srow[k] = (k0 + k >= vlen) ? MASK_VALUE : s;
    }
}

// Softmax over k (512) then out[4 rows][256] = attn @ V. 4 waves = 4 q-rows.
__global__ __launch_bounds__(256) void softmax_pv_kernel(
    const float* __restrict__ scores,  // [B*128][512]
    const float* __restrict__ values,  // [B][512][256]
    float* __restrict__ out)           // [B*128][256]
{
    const int b  = blockIdx.y;
    const int q0 = blockIdx.x * 4;

    __shared__ float attn[4][512];
    const int t = threadIdx.x;
    const int w = t >> 6, lane = t & 63;

    const float* srow = scores + (b * 128 + q0 + w) * 512;
    float sv[8];
#pragma unroll
    for (int j = 0; j < 8; ++j) sv[j] = srow[lane + 64 * j];

    float m = sv[0];
#pragma unroll
    for (int j = 1; j < 8; ++j) m = fmaxf(m, sv[j]);
#pragma unroll
    for (int o = 1; o < 64; o <<= 1) m = fmaxf(m, __shfl_xor(m, o));

    float sum = 0.0f;
#pragma unroll
    for (int j = 0; j < 8; ++j) {
        sv[j] = fast_exp2((sv[j] - m) * LOG2E);
        sum += sv[j];
    }
#pragma unroll
    for (int o = 1; o < 64; o <<= 1) sum += __shfl_xor(sum, o);
    const float rs = fast_rcp(sum);

#pragma unroll
    for (int j = 0; j < 8; ++j) attn[w][lane + 64 * j] = sv[j] * rs;
    __syncthreads();

    const float* V = values + b * 512 * 256;
    float acc[4] = {0.f, 0.f, 0.f, 0.f};
    for (int k = 0; k < 512; ++k) {
        const float v = V[k * 256 + t];        // coalesced
#pragma unroll
        for (int qi = 0; qi < 4; ++qi)
            acc[qi] += attn[qi][k] * v;        // LDS broadcast
    }
#pragma unroll
    for (int qi = 0; qi < 4; ++qi)
        out[(b * 128 + q0 + qi) * 256 + t] = acc[qi];
}

extern "C" void kernel_launch(void* const* d_in, const int* in_sizes, int n_in,
                              void* d_out, int out_size, void* d_ws, size_t ws_size,
                              hipStream_t stream) {
    const float* queries = (const float*)d_in[0];  // [8][128][256]
    const float* keys    = (const float*)d_in[1];  // [8][512][256]
    const float* values  = (const float*)d_in[2];  // [8][512][256]
    const int*   vlens   = (const int*)  d_in[3];  // [8]
    const float* Wq      = (const float*)d_in[4];  // [256][256]
    const float* Wk      = (const float*)d_in[5];  // [256][256]
    const float* wv      = (const float*)d_in[6];  // [256]
    float* out = (float*)d_out;

    float* qproj  = (float*)d_ws;                  // 1024*256
    float* kproj  = qproj + 1024 * 256;            // 4096*256
    float* scores = kproj + 4096 * 256;            // 1024*512

    proj_kernel<<<64,  256, 0, stream>>>(queries, Wq, qproj, SCALE_2LOG2E);
    proj_kernel<<<256, 256, 0, stream>>>(keys,    Wk, kproj, SCALE_2LOG2E);
    score_kernel<<<dim3(16, 8, 8), 256, 0, stream>>>(qproj, kproj, wv, vlens, scores);
    softmax_pv_kernel<<<dim3(32, 8), 256, 0, stream>>>(scores, values, out);
}